// Round 1
// baseline (13892.155 us; speedup 1.0000x reference)
//
#include <hip/hip_runtime.h>
#include <math.h>

// Problem constants
#define BB   16
#define SS   256
#define NV   196
#define DD   768
#define FFD  2048
#define VV   30522
#define NL   6
#define NHH  8
#define HDD  96

// ---------------- block reductions (blockDim.x == 256 -> 4 waves) ----------------
__device__ __forceinline__ float blockSum(float v, float* red) {
  int lane = threadIdx.x & 63, w = threadIdx.x >> 6;
  #pragma unroll
  for (int o = 32; o; o >>= 1) v += __shfl_down(v, o);
  __syncthreads();
  if (lane == 0) red[w] = v;
  __syncthreads();
  return red[0] + red[1] + red[2] + red[3];
}

__device__ __forceinline__ float blockMax(float v, float* red) {
  int lane = threadIdx.x & 63, w = threadIdx.x >> 6;
  #pragma unroll
  for (int o = 32; o; o >>= 1) v = fmaxf(v, __shfl_down(v, o));
  __syncthreads();
  if (lane == 0) red[w] = v;
  __syncthreads();
  return fmaxf(fmaxf(red[0], red[1]), fmaxf(red[2], red[3]));
}

// ---------------- generic batched GEMM: C = alpha*(A @ B^T) + bias, opt ReLU ----
// A: (M,K) row-major, lda. Per-batch offset: zb*bsAb + zh*bsAh  (z = zb*nInner+zh)
// B (transB=0): (N,K) row-major ldb (i.e. W, C=A@W^T). (transB=1): (K,N) row-major ldb.
// remapA: logical row r maps to physical row (r/255)*256 + r%255 (dec slice).
__global__ __launch_bounds__(256) void gemm_k(
    const float* __restrict__ A, int lda, long long bsAb, long long bsAh,
    const float* __restrict__ Bm, int ldb, long long bsBb, long long bsBh, int transB,
    float* __restrict__ C, int ldc, long long bsCb, long long bsCh,
    const float* __restrict__ bias,
    int M, int N, int K, float alpha, int relu, int remapA, int nInner)
{
  int z = blockIdx.z;
  int zb = z / nInner, zh = z - zb * nInner;
  A  += zb * bsAb + zh * bsAh;
  Bm += zb * bsBb + zh * bsBh;
  C  += zb * bsCb + zh * bsCh;

  const int bm = blockIdx.y << 6, bn = blockIdx.x << 6;
  const int tid = threadIdx.x;
  const int tx = tid & 15, ty = tid >> 4;

  __shared__ __align__(16) float As[16][68];
  __shared__ __align__(16) float Bs[16][68];

  // Precompute the 4 A-row pointers this thread loads (fixed across K chunks)
  const float* aptr[4]; bool aval[4];
  {
    int lm0 = tid >> 4;
    #pragma unroll
    for (int p = 0; p < 4; ++p) {
      int gr = bm + lm0 + p * 16;
      aval[p] = gr < M;
      int ar = gr;
      if (remapA) { int bq = gr / 255; ar = bq * 256 + (gr - bq * 255); }
      aptr[p] = A + (long long)ar * lda;
    }
  }
  const float* bptr[4]; bool bval[4];
  if (!transB) {
    int ln0 = tid >> 4;
    #pragma unroll
    for (int p = 0; p < 4; ++p) {
      int gn = bn + ln0 + p * 16;
      bval[p] = gn < N;
      bptr[p] = Bm + (long long)gn * ldb;
    }
  }

  float acc[4][4] = {{0.f}};

  for (int k0 = 0; k0 < K; k0 += 16) {
    int lk = tid & 15;
    int gk = k0 + lk;
    bool kok = gk < K;
    {
      int lm0 = tid >> 4;
      #pragma unroll
      for (int p = 0; p < 4; ++p) {
        float v = 0.f;
        if (aval[p] && kok) v = aptr[p][gk];
        As[lk][lm0 + p * 16] = v;
      }
    }
    if (!transB) {
      int ln0 = tid >> 4;
      #pragma unroll
      for (int p = 0; p < 4; ++p) {
        float v = 0.f;
        if (bval[p] && kok) v = bptr[p][gk];
        Bs[lk][ln0 + p * 16] = v;
      }
    } else {
      int ln = tid & 63;
      int lk0 = tid >> 6;
      int gn = bn + ln;
      #pragma unroll
      for (int p = 0; p < 4; ++p) {
        int kk = lk0 + p * 4;
        int gkk = k0 + kk;
        float v = 0.f;
        if (gn < N && gkk < K) v = Bm[(long long)gkk * ldb + gn];
        Bs[kk][ln] = v;
      }
    }
    __syncthreads();
    #pragma unroll
    for (int kk = 0; kk < 16; ++kk) {
      float4 av = *(const float4*)&As[kk][ty << 2];
      float4 bv = *(const float4*)&Bs[kk][tx << 2];
      float a_[4] = {av.x, av.y, av.z, av.w};
      float b_[4] = {bv.x, bv.y, bv.z, bv.w};
      #pragma unroll
      for (int i = 0; i < 4; ++i)
        #pragma unroll
        for (int j = 0; j < 4; ++j)
          acc[i][j] += a_[i] * b_[j];
    }
    __syncthreads();
  }

  #pragma unroll
  for (int i = 0; i < 4; ++i) {
    int gr = bm + (ty << 2) + i;
    if (gr >= M) continue;
    float* crow = C + (long long)gr * ldc;
    #pragma unroll
    for (int j = 0; j < 4; ++j) {
      int gc = bn + (tx << 2) + j;
      if (gc >= N) continue;
      float v = acc[i][j] * alpha;
      if (bias) v += bias[gc];
      if (relu) v = fmaxf(v, 0.f);
      crow[gc] = v;
    }
  }
}

// ---------------- x = target_embed + sinusoid PE ----------------
__global__ void add_pe_k(const float* __restrict__ te, float* __restrict__ x)
{
  long long i = (long long)blockIdx.x * 256 + threadIdx.x;   // BB*SS*DD total
  int d = (int)(i % DD);
  int s = (int)((i / DD) % SS);
  int i2 = d >> 1;
  const float coef = -logf(10000.f) / (float)DD;
  float ang = (float)s * expf((float)(2 * i2) * coef);
  float pe = (d & 1) ? cosf(ang) : sinf(ang);
  x[i] = te[i] + pe;
}

// ---------------- row softmax over attention scores (opt causal) ----------------
// rows = BB*NHH*SS; row r corresponds to query q = r % SS
__global__ __launch_bounds__(256) void softmax_rows_k(float* __restrict__ sc, int Lk, int causal)
{
  long long r = blockIdx.x;
  int q = (int)(r & (SS - 1));
  float* row = sc + r * (long long)Lk;
  int t = threadIdx.x;
  bool valid = (t < Lk) && (!causal || t <= q);
  float v = valid ? row[t] : -INFINITY;
  __shared__ float red[64];
  float m = blockMax(v, red);
  float e = valid ? expf(v - m) : 0.f;
  float s = blockSum(e, red);
  if (t < Lk) row[t] = e / s;
}

// ---------------- x = LayerNorm(x + t) * w + b (row = 768) ----------------
__global__ __launch_bounds__(256) void add_ln_k(
    float* __restrict__ x, const float* __restrict__ t,
    const float* __restrict__ w, const float* __restrict__ b)
{
  long long r = blockIdx.x;
  float* xr = x + r * DD;
  const float* tr = t + r * DD;
  int tid = threadIdx.x;
  float u[3]; float s = 0.f, sq = 0.f;
  #pragma unroll
  for (int i = 0; i < 3; ++i) {
    int c = tid + (i << 8);
    u[i] = xr[c] + tr[c];
    s += u[i]; sq += u[i] * u[i];
  }
  __shared__ float red[64];
  s  = blockSum(s, red);
  sq = blockSum(sq, red);
  float mean = s * (1.f / 768.f);
  float var  = sq * (1.f / 768.f) - mean * mean;
  float rs = rsqrtf(var + 1e-5f);
  #pragma unroll
  for (int i = 0; i < 3; ++i) {
    int c = tid + (i << 8);
    xr[c] = (u[i] - mean) * rs * w[c] + b[c];
  }
}

// ---------------- F_t = softmax(dec, axis=-1), dec row r -> x row (r/255)*256+r%255 ----
__global__ __launch_bounds__(256) void softmax_d_k(const float* __restrict__ x, float* __restrict__ out)
{
  int r = blockIdx.x;           // 0 .. BB*(SS-1)-1
  int b = r / 255, sI = r - b * 255;
  const float* xr = x + ((long long)(b * 256 + sI)) * DD;
  float* orow = out + (long long)r * DD;
  int t = threadIdx.x;
  float u[3]; float mx = -INFINITY;
  #pragma unroll
  for (int i = 0; i < 3; ++i) { u[i] = xr[t + (i << 8)]; mx = fmaxf(mx, u[i]); }
  __shared__ float red[64];
  float m = blockMax(mx, red);
  float e[3]; float s = 0.f;
  #pragma unroll
  for (int i = 0; i < 3; ++i) { e[i] = expf(u[i] - m); s += e[i]; }
  s = blockSum(s, red);
  float inv = 1.f / s;
  #pragma unroll
  for (int i = 0; i < 3; ++i) orow[t + (i << 8)] = e[i] * inv;
}

// ---------------- host-side launch helpers ----------------
static inline void gemm(hipStream_t st,
    const float* A, int lda, long long bsAb, long long bsAh,
    const float* Bm, int ldb, long long bsBb, long long bsBh, int transB,
    float* C, int ldc, long long bsCb, long long bsCh,
    const float* bias, int M, int N, int K, float alpha, int relu, int remapA,
    int nInner, int nBatch)
{
  dim3 g((N + 63) / 64, (M + 63) / 64, nBatch);
  gemm_k<<<g, 256, 0, st>>>(A, lda, bsAb, bsAh, Bm, ldb, bsBb, bsBh, transB,
                            C, ldc, bsCb, bsCh, bias, M, N, K, alpha, relu, remapA, nInner);
}

extern "C" void kernel_launch(void* const* d_in, const int* in_sizes, int n_in,
                              void* d_out, int out_size, void* d_ws, size_t ws_size,
                              hipStream_t stream)
{
  const float* fv          = (const float*)d_in[0];
  const float* te          = (const float*)d_in[1];
  const float* self_in_w   = (const float*)d_in[2];
  const float* self_in_b   = (const float*)d_in[3];
  const float* self_out_w  = (const float*)d_in[4];
  const float* self_out_b  = (const float*)d_in[5];
  const float* cross_in_w  = (const float*)d_in[6];
  const float* cross_in_b  = (const float*)d_in[7];
  const float* cross_out_w = (const float*)d_in[8];
  const float* cross_out_b = (const float*)d_in[9];
  const float* lin1_w      = (const float*)d_in[10];
  const float* lin1_b      = (const float*)d_in[11];
  const float* lin2_w      = (const float*)d_in[12];
  const float* lin2_b      = (const float*)d_in[13];
  const float* ln_w        = (const float*)d_in[14];
  const float* ln_b        = (const float*)d_in[15];
  const float* fc_out_w    = (const float*)d_in[16];
  float* out = (float*)d_out;

  // workspace layout (floats): x | buf1 (qkv / q+kv / ffn-h) | scores | obuf | tbuf
  float* x    = (float*)d_ws;                       // 4096*768
  float* buf1 = x    + (size_t)4096 * 768;          // 4096*2304
  float* sc   = buf1 + (size_t)4096 * 2304;         // 128*256*256
  float* obuf = sc   + (size_t)128 * 256 * 256;     // 4096*768
  float* tbuf = obuf + (size_t)4096 * 768;          // 4096*768

  const int M = BB * SS;                  // 4096
  const float ishd = 0.10206207261596577f; // 1/sqrt(96)

  add_pe_k<<<dim3((BB * SS * DD) / 256), 256, 0, stream>>>(te, x);

  for (int l = 0; l < NL; ++l) {
    // ======== self attention ========
    gemm(stream, x, DD, 0, 0,
         self_in_w + (size_t)l * 3 * DD * DD, DD, 0, 0, 0,
         buf1, 3 * DD, 0, 0,
         self_in_b + (size_t)l * 3 * DD, M, 3 * DD, DD, 1.f, 0, 0, 1, 1);
    // scores = (q @ k^T) / sqrt(hd) per (b,h)
    gemm(stream, buf1, 3 * DD, (long long)SS * 3 * DD, HDD,
         buf1 + DD, 3 * DD, (long long)SS * 3 * DD, HDD, 0,
         sc, SS, (long long)NHH * SS * SS, (long long)SS * SS,
         nullptr, SS, SS, HDD, ishd, 0, 0, NHH, BB * NHH);
    softmax_rows_k<<<dim3(BB * NHH * SS), 256, 0, stream>>>(sc, SS, 1);
    // o = attn @ v
    gemm(stream, sc, SS, (long long)NHH * SS * SS, (long long)SS * SS,
         buf1 + 2 * DD, 3 * DD, (long long)SS * 3 * DD, HDD, 1,
         obuf, DD, (long long)SS * DD, HDD,
         nullptr, SS, HDD, SS, 1.f, 0, 0, NHH, BB * NHH);
    gemm(stream, obuf, DD, 0, 0,
         self_out_w + (size_t)l * DD * DD, DD, 0, 0, 0,
         tbuf, DD, 0, 0,
         self_out_b + (size_t)l * DD, M, DD, DD, 1.f, 0, 0, 1, 1);
    add_ln_k<<<dim3(M), 256, 0, stream>>>(x, tbuf,
         ln_w + (size_t)(l * 3 + 0) * DD, ln_b + (size_t)(l * 3 + 0) * DD);

    // ======== cross attention ========
    float* qb  = buf1;                      // 4096*768
    float* kvb = buf1 + (size_t)M * DD;     // 3136*1536
    gemm(stream, x, DD, 0, 0,
         cross_in_w + (size_t)l * 3 * DD * DD, DD, 0, 0, 0,
         qb, DD, 0, 0,
         cross_in_b + (size_t)l * 3 * DD, M, DD, DD, 1.f, 0, 0, 1, 1);
    gemm(stream, fv, DD, 0, 0,
         cross_in_w + (size_t)l * 3 * DD * DD + (size_t)DD * DD, DD, 0, 0, 0,
         kvb, 2 * DD, 0, 0,
         cross_in_b + (size_t)l * 3 * DD + DD, BB * NV, 2 * DD, DD, 1.f, 0, 0, 1, 1);
    gemm(stream, qb, DD, (long long)SS * DD, HDD,
         kvb, 2 * DD, (long long)NV * 2 * DD, HDD, 0,
         sc, NV, (long long)NHH * SS * NV, (long long)SS * NV,
         nullptr, SS, NV, HDD, ishd, 0, 0, NHH, BB * NHH);
    softmax_rows_k<<<dim3(BB * NHH * SS), 256, 0, stream>>>(sc, NV, 0);
    gemm(stream, sc, NV, (long long)NHH * SS * NV, (long long)SS * NV,
         kvb + DD, 2 * DD, (long long)NV * 2 * DD, HDD, 1,
         obuf, DD, (long long)SS * DD, HDD,
         nullptr, SS, HDD, NV, 1.f, 0, 0, NHH, BB * NHH);
    gemm(stream, obuf, DD, 0, 0,
         cross_out_w + (size_t)l * DD * DD, DD, 0, 0, 0,
         tbuf, DD, 0, 0,
         cross_out_b + (size_t)l * DD, M, DD, DD, 1.f, 0, 0, 1, 1);
    add_ln_k<<<dim3(M), 256, 0, stream>>>(x, tbuf,
         ln_w + (size_t)(l * 3 + 1) * DD, ln_b + (size_t)(l * 3 + 1) * DD);

    // ======== FFN ========
    gemm(stream, x, DD, 0, 0,
         lin1_w + (size_t)l * FFD * DD, DD, 0, 0, 0,
         buf1, FFD, 0, 0,
         lin1_b + (size_t)l * FFD, M, FFD, DD, 1.f, 1, 0, 1, 1);
    gemm(stream, buf1, FFD, 0, 0,
         lin2_w + (size_t)l * DD * FFD, FFD, 0, 0, 0,
         tbuf, DD, 0, 0,
         lin2_b + (size_t)l * DD, M, DD, FFD, 1.f, 0, 0, 1, 1);
    add_ln_k<<<dim3(M), 256, 0, stream>>>(x, tbuf,
         ln_w + (size_t)(l * 3 + 2) * DD, ln_b + (size_t)(l * 3 + 2) * DD);
  }

  // logits = dec @ fc_out_w^T   (dec rows remapped from x)
  gemm(stream, x, DD, 0, 0,
       fc_out_w, DD, 0, 0, 0,
       out, VV, 0, 0,
       nullptr, BB * (SS - 1), VV, DD, 1.f, 0, 1, 1, 1);
  // F_t = softmax(dec, axis=-1)
  softmax_d_k<<<dim3(BB * (SS - 1)), 256, 0, stream>>>(x, out + (size_t)BB * (SS - 1) * VV);
}